// Round 3
// baseline (200.257 us; speedup 1.0000x reference)
//
#include <hip/hip_runtime.h>

// YOLOv3 decode. R8: sequential-stream hypothesis. R5 (scalar gather),
// R6 (float4 gather), R7 (global_load_lds staging) ALL land at
// 110 MB read / ~53 us = 2.1 TB/s despite 5-8x more bytes nominally in
// flight than latency-hiding requires -> in-flight bytes are not the
// binding variable. Discriminator vs the fast cases (fill 6.8 TB/s, m13
// copy 6.3 TB/s with ~2 loads/wave in flight): those present LONG
// SEQUENTIAL address streams; ours jump every 16 B - 2.7 KB across
// channels and defeat the stream-prefetch path. Fix: one WG per (b,a)
// slice ([85][HW] = up to 920 KB fully contiguous), swept front-to-back
// channel-by-channel. Thread->hw map identical for all channels, so
// best/idx accumulate in REGISTERS: no LDS, no barriers, no shuffles.
// Box channels re-read in the epilogue (per slot) to keep loop VGPRs low.
// 13-scale (HW=169, unaligned) uses the scalar analog. Heavies first.

__device__ __forceinline__ void upd4(float4& best, float4& bidx,
                                     const float4 v, const float ci) {
    if (v.x > best.x) { best.x = v.x; bidx.x = ci; }
    if (v.y > best.y) { best.y = v.y; bidx.y = ci; }
    if (v.z > best.z) { best.z = v.z; bidx.z = ci; }
    if (v.w > best.w) { best.w = v.w; bidx.w = ci; }
}

__device__ __forceinline__ float comp(const float4& v, int k) {
    switch (k) { case 0: return v.x; case 1: return v.y;
                 case 2: return v.z; default: return v.w; }
}

// float4 streaming path. Slice = [85][HW] contiguous for one (b,a).
// SLOTS = ceil((HW/4)/256); thread t owns float4 indices {s*256+t}.
template<int HW, int W, int SLOTS>
__device__ __forceinline__ void decode_stream4(
    const float* __restrict__ in, const float* __restrict__ anch,
    float scale, float inv_case, float th,
    int b, int a, int row_base,
    float* __restrict__ boxes, float* __restrict__ mask)
{
    constexpr int HW4 = HW / 4;
    const int t = threadIdx.x;
    if (SLOTS == 1 && t >= HW4) return;          // tail threads idle; no barriers

    const float4* __restrict__ base =
        reinterpret_cast<const float4*>(in) + ((size_t)b * 255 + (size_t)a * 85) * HW4;

    // compile-time-full or thread-predicated slot activity
    auto act = [&](int s) { return (s + 1) * 256 <= HW4 ? true : (s * 256 + t < HW4); };

    float4 best[SLOTS], bidx[SLOTS];
#pragma unroll
    for (int s = 0; s < SLOTS; ++s) {
        best[s] = make_float4(-1e30f, -1e30f, -1e30f, -1e30f);
        bidx[s] = make_float4(0.f, 0.f, 0.f, 0.f);
    }

    // class channels 5..84: monotonically increasing addresses, depth-2
    // software pipeline (next channel's loads issued before current's compares).
    float4 cur[SLOTS], nxt[SLOTS];
#pragma unroll
    for (int s = 0; s < SLOTS; ++s)
        if (act(s)) cur[s] = base[(size_t)5 * HW4 + s * 256 + t];

#pragma unroll 2
    for (int c = 5; c < 84; ++c) {
#pragma unroll
        for (int s = 0; s < SLOTS; ++s)
            if (act(s)) nxt[s] = base[(size_t)(c + 1) * HW4 + s * 256 + t];
        const float ci = (float)(c - 5);
#pragma unroll
        for (int s = 0; s < SLOTS; ++s)
            upd4(best[s], bidx[s], cur[s], ci);
#pragma unroll
        for (int s = 0; s < SLOTS; ++s)
            cur[s] = nxt[s];
    }
#pragma unroll
    for (int s = 0; s < SLOTS; ++s)
        upd4(best[s], bidx[s], cur[s], 79.f);

    // epilogue: per slot, fetch the 5 box channels (L3-resident), decode, store
    const float a0 = anch[2 * a + 0], a1 = anch[2 * a + 1];
#pragma unroll
    for (int s = 0; s < SLOTS; ++s) {
        if (!act(s)) continue;
        float4 bx0 = base[(size_t)0 * HW4 + s * 256 + t];
        float4 bx1 = base[(size_t)1 * HW4 + s * 256 + t];
        float4 bx2 = base[(size_t)2 * HW4 + s * 256 + t];
        float4 bx3 = base[(size_t)3 * HW4 + s * 256 + t];
        float4 bx4 = base[(size_t)4 * HW4 + s * 256 + t];
#pragma unroll
        for (int k = 0; k < 4; ++k) {
            const int hw = (s * 256 + t) * 4 + k;
            const int hh = hw / W;                 // compile-time W -> magic mul
            const int ww = hw - hh * W;
            const float e0 = comp(bx0, k);
            const float px = 1.f / (1.f + __expf(-e0));
            const float cx = ((float)ww + comp(bx1, k)) * scale;
            const float cy = ((float)hh + comp(bx2, k)) * scale;
            const float bw = a0 * __expf(comp(bx3, k)) * inv_case;
            const float bh = a1 * __expf(comp(bx4, k)) * inv_case;
            const int row = row_base + (b * HW + hw) * 3 + a;
            float2* ob2 = reinterpret_cast<float2*>(boxes + (size_t)row * 6);
            ob2[0] = make_float2(px, cx);
            ob2[1] = make_float2(cy, bw);
            ob2[2] = make_float2(bh, comp(bidx[s], k));
            mask[row] = (e0 > th) ? 1.0f : 0.0f;
        }
    }
}

// scalar streaming path for 13x13 (HW=169: channel stride 676 B, not
// 16B-aligned; 5.7 MB total so scalar is fine). Same structure.
__device__ __forceinline__ void decode_stream13(
    const float* __restrict__ in, const float* __restrict__ anch,
    float scale, float inv_case, float th,
    int b, int a, int row_base,
    float* __restrict__ boxes, float* __restrict__ mask)
{
    constexpr int HW = 169, W = 13;
    const int t = threadIdx.x;
    if (t >= HW) return;

    const float* __restrict__ base = in + ((size_t)b * 255 + (size_t)a * 85) * HW + t;

    float best = -1e30f, bidx = 0.f;
    float cur = base[(size_t)5 * HW], nxt;
#pragma unroll 2
    for (int c = 5; c < 84; ++c) {
        nxt = base[(size_t)(c + 1) * HW];
        if (cur > best) { best = cur; bidx = (float)(c - 5); }
        cur = nxt;
    }
    if (cur > best) { best = cur; bidx = 79.f; }

    const float e0 = base[0 * (size_t)HW];
    const float o1 = base[1 * (size_t)HW];
    const float o2 = base[2 * (size_t)HW];
    const float o3 = base[3 * (size_t)HW];
    const float o4 = base[4 * (size_t)HW];

    const int hh = t / W;
    const int ww = t - hh * W;
    const float px = 1.f / (1.f + __expf(-e0));
    const float cx = ((float)ww + o1) * scale;
    const float cy = ((float)hh + o2) * scale;
    const float bw = anch[2 * a + 0] * __expf(o3) * inv_case;
    const float bh = anch[2 * a + 1] * __expf(o4) * inv_case;
    const int row = row_base + (b * HW + t) * 3 + a;
    float2* ob2 = reinterpret_cast<float2*>(boxes + (size_t)row * 6);
    ob2[0] = make_float2(px, cx);
    ob2[1] = make_float2(cy, bw);
    ob2[2] = make_float2(bh, bidx);
    mask[row] = (e0 > th) ? 1.0f : 0.0f;
}

__global__ __launch_bounds__(256) void detector_kernel(
    const float* __restrict__ in13, const float* __restrict__ in26,
    const float* __restrict__ in52,
    const float* __restrict__ a13, const float* __restrict__ a26,
    const float* __restrict__ a52,
    const float* __restrict__ thp, const int* __restrict__ casep,
    float* __restrict__ boxes, float* __restrict__ mask, int B)
{
    const int gx = blockIdx.x;
    const float th       = thp[0];
    const float inv_case = 1.0f / (float)casep[0];
    const int n52 = B * 3;                       // heavy slices first

    if (gx < n52) {
        const int b = gx / 3, a = gx - b * 3;
        decode_stream4<2704, 52, 3>(in52, a52, 8.0f * inv_case, inv_case, th,
                                    b, a, B * (169 + 676) * 3, boxes, mask);
    } else if (gx < 2 * n52) {
        const int u = gx - n52;
        const int b = u / 3, a = u - b * 3;
        decode_stream4<676, 26, 1>(in26, a26, 16.0f * inv_case, inv_case, th,
                                   b, a, B * 169 * 3, boxes, mask);
    } else {
        const int u = gx - 2 * n52;
        const int b = u / 3, a = u - b * 3;
        decode_stream13(in13, a13, 32.0f * inv_case, inv_case, th,
                        b, a, 0, boxes, mask);
    }
}

extern "C" void kernel_launch(void* const* d_in, const int* in_sizes, int n_in,
                              void* d_out, int out_size, void* d_ws, size_t ws_size,
                              hipStream_t stream) {
    const float* in13 = (const float*)d_in[0];
    const float* in26 = (const float*)d_in[1];
    const float* in52 = (const float*)d_in[2];
    const float* a13  = (const float*)d_in[3];
    const float* a26  = (const float*)d_in[4];
    const float* a52  = (const float*)d_in[5];
    const float* thp  = (const float*)d_in[6];
    const int*   casep = (const int*)d_in[7];

    const int B = in_sizes[0] / (255 * 169);

    const int nrows = B * (169 + 676 + 2704) * 3;
    float* boxes = (float*)d_out;
    float* mask  = (float*)d_out + (size_t)nrows * 6;

    dim3 grid(B * 9);   // B*3 (52, heavy) + B*3 (26) + B*3 (13)
    detector_kernel<<<grid, 256, 0, stream>>>(
        in13, in26, in52, a13, a26, a52, thp, casep, boxes, mask, B);
}

// Round 4
// 171.482 us; speedup vs baseline: 1.1678x; 1.1678x over previous
//
#include <hip/hip_runtime.h>

// YOLOv3 decode. R9: L1-bypass (nt) test on the proven R5 structure.
// Invariant found across R5-R8: per-CU read delivery pinned at ~7-8 GB/s
// (~2.1 TB/s chip) regardless of mechanism (scalar / float4 / LDS-DMA /
// sequential), waves/CU (1-21), or nominal bytes in flight (6-100 KB/CU).
// Little's law @ ~430ns says effective outstanding ~ 27 lines/CU in every
// case -> fixed per-CU miss-tracking budget (L1/TCP MSHRs). Copy's 3.15
// TB/s read fits the same 27-line cap at stream-reduced latency.
// Lever: __builtin_nontemporal_load on all input reads (read-exactly-once
// data, zero reuse) -> nt policy skips L1 allocation; if nt requests are
// tracked in the deeper L2/return queue instead of L1 MSHRs, the in-flight
// cap rises and BW scales. Single-bit delta on the 53us R5 kernel:
// same addresses, same mapping, same occupancy (VGPR 24, 21 waves/CU).

#define NCLS 80

template<int HW, int W>
__device__ __forceinline__ void decode4(
    const float* __restrict__ in, const float* __restrict__ anch,
    float scale, float inv_case, float th,
    int a, int t, int row_base, int B,
    float* __restrict__ boxes, float* __restrict__ mask)
{
    if (t >= B * HW * 4) return;
    const int rt  = t >> 2;          // row-in-scale-anchor: b*HW + hw
    const int seg = t & 3;           // class segment 0..3
    const int b   = rt / HW;         // compile-time divisor -> magic mul
    const int hw  = rt - b * HW;

    const float* p = in + ((size_t)b * 255 + (size_t)a * 85) * HW + hw;

    // 20 independent class loads for this segment, then compare.
    // nt: bypass L1 allocation (read-once data).
    const float* pc = p + (size_t)(5 + seg * 20) * HW;
    float v[20];
#pragma unroll
    for (int j = 0; j < 20; ++j)
        v[j] = __builtin_nontemporal_load(&pc[(size_t)j * HW]);

    float best = v[0];
    int   bi   = seg * 20;
#pragma unroll
    for (int j = 1; j < 20; ++j)
        if (v[j] > best) { best = v[j]; bi = seg * 20 + j; }

    // box channels: all 4 segs load the same addresses (same line -> one
    // coalesced request per wave), issued before the reduce so latency
    // overlaps the shuffles.
    float o0 = __builtin_nontemporal_load(&p[0 * (size_t)HW]);
    float o1 = __builtin_nontemporal_load(&p[1 * (size_t)HW]);
    float o2 = __builtin_nontemporal_load(&p[2 * (size_t)HW]);
    float o3 = __builtin_nontemporal_load(&p[3 * (size_t)HW]);
    float o4 = __builtin_nontemporal_load(&p[4 * (size_t)HW]);

    // quad butterfly reduce: max with smallest-index tie-break (jnp.argmax)
#pragma unroll
    for (int m = 1; m <= 2; m <<= 1) {
        float ob = __shfl_xor(best, m);
        int   oi = __shfl_xor(bi,   m);
        if (ob > best || (ob == best && oi < bi)) { best = ob; bi = oi; }
    }

    if (seg == 0) {
        int h = hw / W;
        int w = hw - h * W;
        float px = 1.0f / (1.0f + __expf(-o0));
        float cx = ((float)w + o1) * scale;
        float cy = ((float)h + o2) * scale;
        float bw = anch[2 * a + 0] * __expf(o3) * inv_case;
        float bh = anch[2 * a + 1] * __expf(o4) * inv_case;

        int row = row_base + rt * 3 + a;     // seg0 lanes -> 16 consecutive rt
        float2* ob2 = reinterpret_cast<float2*>(boxes + (size_t)row * 6);
        ob2[0] = make_float2(px, cx);
        ob2[1] = make_float2(cy, bw);
        ob2[2] = make_float2(bh, (float)bi);
        mask[row] = (o0 > th) ? 1.0f : 0.0f;
    }
}

__global__ __launch_bounds__(256) void detector_kernel(
    const float* __restrict__ in13, const float* __restrict__ in26,
    const float* __restrict__ in52,
    const float* __restrict__ a13, const float* __restrict__ a26,
    const float* __restrict__ a52,
    const float* __restrict__ thp, const int* __restrict__ casep,
    float* __restrict__ boxes, float* __restrict__ mask,
    int B, int nb52, int nb26)
{
    const int a  = blockIdx.y;
    const int bx = blockIdx.x;
    const float th       = thp[0];
    const float inv_case = 1.0f / (float)casep[0];

    if (bx < nb52) {
        int t = bx * 256 + threadIdx.x;
        decode4<2704, 52>(in52, a52, 8.0f * inv_case, inv_case, th,
                          a, t, B * (169 + 676) * 3, B, boxes, mask);
    } else if (bx < nb52 + nb26) {
        int t = (bx - nb52) * 256 + threadIdx.x;
        decode4<676, 26>(in26, a26, 16.0f * inv_case, inv_case, th,
                         a, t, B * 169 * 3, B, boxes, mask);
    } else {
        int t = (bx - nb52 - nb26) * 256 + threadIdx.x;
        decode4<169, 13>(in13, a13, 32.0f * inv_case, inv_case, th,
                         a, t, 0, B, boxes, mask);
    }
}

extern "C" void kernel_launch(void* const* d_in, const int* in_sizes, int n_in,
                              void* d_out, int out_size, void* d_ws, size_t ws_size,
                              hipStream_t stream) {
    const float* in13 = (const float*)d_in[0];
    const float* in26 = (const float*)d_in[1];
    const float* in52 = (const float*)d_in[2];
    const float* a13  = (const float*)d_in[3];
    const float* a26  = (const float*)d_in[4];
    const float* a52  = (const float*)d_in[5];
    const float* thp  = (const float*)d_in[6];
    const int*   casep = (const int*)d_in[7];

    const int B = in_sizes[0] / (255 * 169);

    const int nb52 = (B * 2704 * 4 + 255) / 256;
    const int nb26 = (B * 676  * 4 + 255) / 256;
    const int nb13 = (B * 169  * 4 + 255) / 256;

    const int nrows = B * (169 + 676 + 2704) * 3;
    float* boxes = (float*)d_out;
    float* mask  = (float*)d_out + (size_t)nrows * 6;

    dim3 grid(nb52 + nb26 + nb13, 3);
    detector_kernel<<<grid, 256, 0, stream>>>(
        in13, in26, in52, a13, a26, a52, thp, casep,
        boxes, mask, B, nb52, nb26);
}

// Round 6
// 169.537 us; speedup vs baseline: 1.1812x; 1.0115x over previous
//
#include <hip/hip_runtime.h>

// YOLOv3 decode. R10b: compile fix of R10 (nt builtin needs a clang
// ext_vector pointer, not HIP_vector_type float4*). Theory unchanged:
// stream-quality x occupancy. Ledger: R5 8.6 GB/s/CU (21 waves, 64B
// segments), R6 7.8 (12 waves, 256B), R7 8.5 (LDS-DMA, 2.7KB bursts),
// R8-heavy 11 GB/s/CU with only 4-5 waves (920KB sequential slice
// streams; lost to 160 idle CUs), R9 nt-bypass null. RMSNorm reference:
// 19 GB/s/CU (sequential 16B/lane + high occupancy). => currency =
// per-wave stream quality x waves/CU. Thread owns one float4-column of
// one (b,a) slice, sweeps 40 channels (2-seg split across lane halves);
// wave-load = 2x512B fully-consumed bursts; thread walk = monotone
// through ~430KB half-slice. 52: 507 WGs (128 cols/WG exact), 26: 127
// WGs, 13: proven scalar path. 889 equal-weight WGs -> ~8 waves/CU.

typedef float vf4 __attribute__((ext_vector_type(4)));

__device__ __forceinline__ float4 ntld4(const float4* p) {
    const vf4 v = __builtin_nontemporal_load(reinterpret_cast<const vf4*>(p));
    return make_float4(v.x, v.y, v.z, v.w);
}

// ---------- streaming column path (52 and 26 scales) ----------
template<int HW4, int W>
__device__ __forceinline__ void decode_stream2(
    const float* __restrict__ in, const float* __restrict__ anch,
    float scale, float inv_case, float th,
    int col, int seg, int ncols, int row_base,
    float* __restrict__ boxes, float* __restrict__ mask)
{
    constexpr int HW = HW4 * 4;
    if (col >= ncols) return;            // lane and lane^32 share col -> pair-safe
    const int slice = col / HW4;         // b*3 + a   (compile-time HW4 -> magic mul)
    const int hw4   = col - slice * HW4;
    const int b     = slice / 3;
    const int a     = slice - b * 3;

    const float4* s4 = reinterpret_cast<const float4*>(in)
                     + (size_t)slice * 85 * HW4 + hw4;
    const float4* cp = s4 + (size_t)(5 + seg * 40) * HW4;

    float4 best = make_float4(-1e30f, -1e30f, -1e30f, -1e30f);
    int4   bidx = make_int4(0, 0, 0, 0);
#pragma unroll 8
    for (int j = 0; j < 40; ++j) {
        const float4 v = ntld4(&cp[(size_t)j * HW4]);
        if (v.x > best.x) { best.x = v.x; bidx.x = j; }
        if (v.y > best.y) { best.y = v.y; bidx.y = j; }
        if (v.z > best.z) { best.z = v.z; bidx.z = j; }
        if (v.w > best.w) { best.w = v.w; bidx.w = j; }
    }
    const int g = seg * 40;
    bidx.x += g; bidx.y += g; bidx.z += g; bidx.w += g;

    // combine the two channel halves: xor-32 butterfly, smaller-index tie-break
    {
        float ob; int oi;
        ob = __shfl_xor(best.x, 32); oi = __shfl_xor(bidx.x, 32);
        if (ob > best.x || (ob == best.x && oi < bidx.x)) { best.x = ob; bidx.x = oi; }
        ob = __shfl_xor(best.y, 32); oi = __shfl_xor(bidx.y, 32);
        if (ob > best.y || (ob == best.y && oi < bidx.y)) { best.y = ob; bidx.y = oi; }
        ob = __shfl_xor(best.z, 32); oi = __shfl_xor(bidx.z, 32);
        if (ob > best.z || (ob == best.z && oi < bidx.z)) { best.z = ob; bidx.z = oi; }
        ob = __shfl_xor(best.w, 32); oi = __shfl_xor(bidx.w, 32);
        if (ob > best.w || (ob == best.w && oi < bidx.w)) { best.w = ob; bidx.w = oi; }
    }
    if (seg) return;                     // seg0 lanes finalize

    const float4 o0 = ntld4(&s4[0]);
    const float4 o1 = ntld4(&s4[(size_t)1 * HW4]);
    const float4 o2 = ntld4(&s4[(size_t)2 * HW4]);
    const float4 o3 = ntld4(&s4[(size_t)3 * HW4]);
    const float4 o4 = ntld4(&s4[(size_t)4 * HW4]);
    const float a0 = anch[2 * a + 0], a1 = anch[2 * a + 1];

    const float e0[4] = { o0.x, o0.y, o0.z, o0.w };
    const float e1[4] = { o1.x, o1.y, o1.z, o1.w };
    const float e2[4] = { o2.x, o2.y, o2.z, o2.w };
    const float e3[4] = { o3.x, o3.y, o3.z, o3.w };
    const float e4[4] = { o4.x, o4.y, o4.z, o4.w };
    const int   bi[4] = { bidx.x, bidx.y, bidx.z, bidx.w };
#pragma unroll
    for (int k = 0; k < 4; ++k) {
        const int hw = hw4 * 4 + k;
        const int hh = hw / W;           // compile-time W -> magic mul
        const int ww = hw - hh * W;
        const float px = 1.f / (1.f + __expf(-e0[k]));
        const float cx = ((float)ww + e1[k]) * scale;
        const float cy = ((float)hh + e2[k]) * scale;
        const float bw = a0 * __expf(e3[k]) * inv_case;
        const float bh = a1 * __expf(e4[k]) * inv_case;
        const int row = row_base + (b * HW + hw) * 3 + a;
        float2* ob2 = reinterpret_cast<float2*>(boxes + (size_t)row * 6);
        ob2[0] = make_float2(px, cx);
        ob2[1] = make_float2(cy, bw);
        ob2[2] = make_float2(bh, (float)bi[k]);
        mask[row] = (e0[k] > th) ? 1.0f : 0.0f;
    }
}

// ---------- scalar path (13x13 only; HW=169 odd) ----------
template<int HW, int W>
__device__ __forceinline__ void decode4(
    const float* __restrict__ in, const float* __restrict__ anch,
    float scale, float inv_case, float th,
    int a, int t, int row_base, int B,
    float* __restrict__ boxes, float* __restrict__ mask)
{
    if (t >= B * HW * 4) return;
    const int rt  = t >> 2;
    const int seg = t & 3;
    const int b   = rt / HW;
    const int hw  = rt - b * HW;

    const float* p = in + ((size_t)b * 255 + (size_t)a * 85) * HW + hw;

    const float* pc = p + (size_t)(5 + seg * 20) * HW;
    float v[20];
#pragma unroll
    for (int j = 0; j < 20; ++j)
        v[j] = __builtin_nontemporal_load(&pc[(size_t)j * HW]);

    float best = v[0];
    int   bi   = seg * 20;
#pragma unroll
    for (int j = 1; j < 20; ++j)
        if (v[j] > best) { best = v[j]; bi = seg * 20 + j; }

    float o0 = p[0 * (size_t)HW];
    float o1 = p[1 * (size_t)HW];
    float o2 = p[2 * (size_t)HW];
    float o3 = p[3 * (size_t)HW];
    float o4 = p[4 * (size_t)HW];

#pragma unroll
    for (int m = 1; m <= 2; m <<= 1) {
        float ob = __shfl_xor(best, m);
        int   oi = __shfl_xor(bi,   m);
        if (ob > best || (ob == best && oi < bi)) { best = ob; bi = oi; }
    }

    if (seg == 0) {
        int h = hw / W;
        int w = hw - h * W;
        float px = 1.0f / (1.0f + __expf(-o0));
        float cx = ((float)w + o1) * scale;
        float cy = ((float)h + o2) * scale;
        float bw = anch[2 * a + 0] * __expf(o3) * inv_case;
        float bh = anch[2 * a + 1] * __expf(o4) * inv_case;

        int row = row_base + rt * 3 + a;
        float2* ob2 = reinterpret_cast<float2*>(boxes + (size_t)row * 6);
        ob2[0] = make_float2(px, cx);
        ob2[1] = make_float2(cy, bw);
        ob2[2] = make_float2(bh, (float)bi);
        mask[row] = (o0 > th) ? 1.0f : 0.0f;
    }
}

__global__ __launch_bounds__(256) void detector_kernel(
    const float* __restrict__ in13, const float* __restrict__ in26,
    const float* __restrict__ in52,
    const float* __restrict__ a13, const float* __restrict__ a26,
    const float* __restrict__ a52,
    const float* __restrict__ thp, const int* __restrict__ casep,
    float* __restrict__ boxes, float* __restrict__ mask,
    int B, int nwg52, int nwg26, int nb13)
{
    const int gx   = blockIdx.x;
    const int tid  = threadIdx.x;
    const int wv   = tid >> 6;
    const int lane = tid & 63;
    const float th       = thp[0];
    const float inv_case = 1.0f / (float)casep[0];

    if (gx < nwg52) {
        const int col = gx * 128 + wv * 32 + (lane & 31);
        decode_stream2<676, 52>(in52, a52, 8.0f * inv_case, inv_case, th,
                                col, lane >> 5, B * 3 * 676,
                                B * (169 + 676) * 3, boxes, mask);
    } else if (gx < nwg52 + nwg26) {
        const int col = (gx - nwg52) * 128 + wv * 32 + (lane & 31);
        decode_stream2<169, 26>(in26, a26, 16.0f * inv_case, inv_case, th,
                                col, lane >> 5, B * 3 * 169,
                                B * 169 * 3, boxes, mask);
    } else {
        const int u = gx - nwg52 - nwg26;
        const int a = u / nb13;                    // nb13 blocks per anchor
        const int t = (u - a * nb13) * 256 + tid;
        decode4<169, 13>(in13, a13, 32.0f * inv_case, inv_case, th,
                         a, t, 0, B, boxes, mask);
    }
}

extern "C" void kernel_launch(void* const* d_in, const int* in_sizes, int n_in,
                              void* d_out, int out_size, void* d_ws, size_t ws_size,
                              hipStream_t stream) {
    const float* in13 = (const float*)d_in[0];
    const float* in26 = (const float*)d_in[1];
    const float* in52 = (const float*)d_in[2];
    const float* a13  = (const float*)d_in[3];
    const float* a26  = (const float*)d_in[4];
    const float* a52  = (const float*)d_in[5];
    const float* thp  = (const float*)d_in[6];
    const int*   casep = (const int*)d_in[7];

    const int B = in_sizes[0] / (255 * 169);

    const int nwg52 = (B * 3 * 676 + 127) / 128;   // columns / (128 cols per WG)
    const int nwg26 = (B * 3 * 169 + 127) / 128;
    const int nb13  = (B * 169 * 4 + 255) / 256;   // blocks per anchor, scalar path

    const int nrows = B * (169 + 676 + 2704) * 3;
    float* boxes = (float*)d_out;
    float* mask  = (float*)d_out + (size_t)nrows * 6;

    dim3 grid(nwg52 + nwg26 + 3 * nb13);
    detector_kernel<<<grid, 256, 0, stream>>>(
        in13, in26, in52, a13, a26, a52, thp, casep,
        boxes, mask, B, nwg52, nwg26, nb13);
}